// Round 10
// baseline (289.316 us; speedup 1.0000x reference)
//
#include <hip/hip_runtime.h>
#include <hip/hip_bf16.h>
#include <cstdint>
#include <cstddef>

constexpr int C_  = 256;
constexpr int H_  = 224;
constexpr int W_  = 224;
constexpr int P_  = 49;
constexpr int M_  = 1024;
constexpr int HW_ = H_ * W_;

constexpr size_t IMG_ELEMS = (size_t)4 * C_ * H_ * W_;
constexpr size_t SCO_ELEMS = (size_t)4 * M_ * P_ * P_;
constexpr size_t OFF_SC  = IMG_ELEMS;
constexpr size_t OFF_COV = OFF_SC  + SCO_ELEMS;
constexpr size_t OFF_L   = OFF_COV + SCO_ELEMS;
constexpr size_t OFF_EC  = OFF_L   + SCO_ELEMS;

typedef __attribute__((ext_vector_type(8))) short short8;
typedef __attribute__((ext_vector_type(4))) float f32x4;

// Workspace: patch-major bf16 Ec staging, 56 p-slots per (bm,c) row (112B).
constexpr size_t WS_ROW   = 56;
constexpr size_t WS_PATCH = (size_t)C_ * WS_ROW;              // 14336 elems
constexpr size_t WS_NEED  = (size_t)4096 * WS_PATCH * 2;      // 117,440,512 B

// LDS byte map (compute kernel, 37,888 B -> 4 blocks/CU):
//   sA  : [0, 25088)        49 rows x 512B bf16, row-XOR-swizzled
//   Gb  : [25088, 31360)    49 rows x 128B bf16 (G - u); Lb overlays after cov
//   Scb : [31360, 37632)    49 rows x 128B bf16 Sc
//   u   : [37632, 37888)    64 f32
// G lives in MFMA accumulators; softmax in-register; fp32 Sc carried in regs
// to the L epilogue; T2 = rowmean of the cov accumulator (exact identity).
// Sc/cov/L global stores DEFERRED to after the last barrier (re-read from
// bf16 Scb/Lb; rel err 0.4% << tolerance) so no mid-kernel vmcnt(0) barrier
// drains on global stores.
// Overflow-read audit: G/cov MFMA garbage lands only in discarded D rows/
// cols; Ec MFMA's A-fragment is explicitly masked to 0 for k>=49 (sA rows
// 49..63 are never written), so no 0*NaN path remains.
constexpr int SA_OFF  = 0;
constexpr int GB_OFF  = 25088;
constexpr int SCB_OFF = 31360;
constexpr int U_OFF   = 37632;
constexpr int SMEM_BYTES = 37888;

__device__ __forceinline__ int srowswz(int r) { return ((r ^ (r >> 3)) & 7) << 4; }

template<bool SPLIT>
__global__ __launch_bounds__(256, 4)
void psa_kernel(const float* __restrict__ x, const float* __restrict__ betap,
                float* __restrict__ out_img, float* __restrict__ out_sc,
                float* __restrict__ out_cov, float* __restrict__ out_l,
                float* __restrict__ out_ec,
                __hip_bfloat16* __restrict__ ws_ec)
{
    __shared__ __align__(16) unsigned char smem[SMEM_BYTES];
    float* uArr = (float*)(smem + U_OFF);

    const int tid = threadIdx.x;
    const int bid = blockIdx.x;
    const int bm  = ((bid & 7) << 9) | (bid >> 3);   // XCD-bijective swizzle
    const int b   = bm >> 10;
    const int m   = bm & (M_ - 1);
    const int mh  = m >> 5;
    const int mw  = m & 31;
    const float beta = betap[0];
    const size_t xpatch = (((size_t)b * C_ * H_) + (size_t)mh * 7) * W_ + (size_t)mw * 7;

    const int wid = tid >> 6, lane = tid & 63, l15 = lane & 15, lh = lane >> 4;

    // ---- Phase 0: stage x -> sA. lane = token p (7x28B segments per load
    // instr, ~10 lines vs 64 with lane=channel); wave wid covers c in
    // [64wid, 64wid+64). ----
    {
        const int p = lane;
        if (p < P_) {
            const int i = p / 7, j = p - 7 * (p / 7);
            const float* xp = x + xpatch + (size_t)i * W_ + j + (size_t)(64 * wid) * HW_;
            const int swzp = srowswz(p);
            unsigned char* sbase = smem + SA_OFF + p * 512 + 128 * wid;
            #pragma unroll 32
            for (int k = 0; k < 64; ++k) {
                const float v = xp[(size_t)k * HW_];
                // (2c)^swz = 128*wid + ((2k)^swz) since 2k^swz < 128
                *(__hip_bfloat16*)(sbase + ((2 * k) ^ swzp)) = __float2bfloat16(v);
            }
        }
    }
    __syncthreads();

    // ---- Phase 1: G = A A^T (MFMA, K=256); G stays in registers ----
    f32x4 gacc[4] = {f32x4{0,0,0,0}, f32x4{0,0,0,0}, f32x4{0,0,0,0}, f32x4{0,0,0,0}};
    {
        const int arow = 16 * wid + l15;
        #pragma unroll
        for (int kc = 0; kc < 8; ++kc) {
            const int cb = 64 * kc + 16 * lh;
            const short8 af = *(const short8*)(smem + SA_OFF + arow * 512 + (cb ^ srowswz(arow)));
            #pragma unroll
            for (int t = 0; t < 4; ++t) {
                const int brow = 16 * t + l15;
                const short8 bf = *(const short8*)(smem + SA_OFF + brow * 512 + (cb ^ srowswz(brow)));
                gacc[t] = __builtin_amdgcn_mfma_f32_16x16x32_bf16(af, bf, gacc[t], 0, 0, 0);
            }
        }
    }

    // ---- Phase 2: in-register row stats (lane holds G[p][q], p=16wid+4lh+r,
    // q=16t+l15); u = rowmean (G symmetric) ----
    float mx[4];
    {
        #pragma unroll
        for (int r = 0; r < 4; ++r) {
            const int p = 16 * wid + 4 * lh + r;
            float m_ = fmaxf(fmaxf(gacc[0][r], gacc[1][r]), gacc[2][r]);
            m_ = fmaxf(m_, (l15 == 0) ? gacc[3][r] : -3.4e38f);
            float s_ = gacc[0][r] + gacc[1][r] + gacc[2][r] + ((l15 == 0) ? gacc[3][r] : 0.f);
            #pragma unroll
            for (int d = 1; d < 16; d <<= 1) {
                m_ = fmaxf(m_, __shfl_xor(m_, d));
                s_ += __shfl_xor(s_, d);
            }
            mx[r] = m_;
            if (l15 == 0 && p <= 48) uArr[p] = s_ * (1.f / 49.f);
        }
    }
    __syncthreads();

    // ---- Phase 3: Gb = bf16(G-u); in-reg exp/rowsum/scale; Scb (global Sc
    // store deferred) ----
    float sc[4][4];   // fp32 Sc carried to the L epilogue
    {
        #pragma unroll
        for (int r = 0; r < 4; ++r) {
            const int p = 16 * wid + 4 * lh + r;
            if (p <= 48) {
                #pragma unroll
                for (int t = 0; t < 4; ++t) {
                    const int qv = 16 * t + l15;
                    const float gv = (qv <= 48) ? (gacc[t][r] - uArr[qv]) : 0.f;
                    *(__hip_bfloat16*)(smem + GB_OFF + p * 128 + ((2 * qv) ^ srowswz(p))) =
                        __float2bfloat16(gv);
                }
            }
            float e[4];
            #pragma unroll
            for (int t = 0; t < 4; ++t) {
                const int qv = 16 * t + l15;
                e[t] = (qv <= 48) ? __expf(gacc[t][r] - mx[r]) : 0.f;
            }
            float s_ = e[0] + e[1] + e[2] + e[3];
            #pragma unroll
            for (int d = 1; d < 16; d <<= 1) s_ += __shfl_xor(s_, d);
            const float rinv = 1.f / s_;
            #pragma unroll
            for (int t = 0; t < 4; ++t) sc[t][r] = e[t] * rinv;
            if (p <= 48) {
                #pragma unroll
                for (int t = 0; t < 4; ++t) {
                    const int qv = 16 * t + l15;
                    *(__hip_bfloat16*)(smem + SCB_OFF + p * 128 + ((2 * qv) ^ srowswz(p))) =
                        __float2bfloat16(sc[t][r]);        // qv>48 stores 0
                    if (!SPLIT && qv <= 48)
                        out_sc[(size_t)bm * (P_ * P_) + p * 49 + qv] = sc[t][r];
                }
            }
        }
    }
    __syncthreads();

    // ---- Phase 4: cov MFMA: cacc = Gb . Scb^T (K=64); T2 = rowmean in-reg ----
    f32x4 cacc[4] = {f32x4{0,0,0,0}, f32x4{0,0,0,0}, f32x4{0,0,0,0}, f32x4{0,0,0,0}};
    {
        const int arow = 16 * wid + l15;
        #pragma unroll
        for (int kc = 0; kc < 2; ++kc) {
            const int cb = 64 * kc + 16 * lh;
            const short8 af = *(const short8*)(smem + GB_OFF + arow * 128 + (cb ^ srowswz(arow)));
            #pragma unroll
            for (int t = 0; t < 4; ++t) {
                const int brow = 16 * t + l15;
                const short8 bf = *(const short8*)(smem + SCB_OFF + brow * 128 + (cb ^ srowswz(brow)));
                cacc[t] = __builtin_amdgcn_mfma_f32_16x16x32_bf16(af, bf, cacc[t], 0, 0, 0);
            }
        }
    }
    float t2[4];
    {
        #pragma unroll
        for (int r = 0; r < 4; ++r) {
            float s_ = cacc[0][r] + cacc[1][r] + cacc[2][r] + ((l15 == 0) ? cacc[3][r] : 0.f);
            #pragma unroll
            for (int d = 1; d < 16; d <<= 1) s_ += __shfl_xor(s_, d);
            t2[r] = s_ * (1.f / 49.f);
        }
    }
    __syncthreads();   // cov reads done before Lb overlays Gb

    // ---- Phase 5: cv = (cacc - T2)/49; L = Sc + cv; Lb LDS write (global
    // cov/L stores deferred) ----
    {
        #pragma unroll
        for (int t = 0; t < 4; ++t) {
            const int qv = 16 * t + l15;
            #pragma unroll
            for (int r = 0; r < 4; ++r) {
                const int p = 16 * wid + 4 * lh + r;
                if (p <= 48 && qv <= 48) {
                    const float cv = (cacc[t][r] - t2[r]) * (1.f / 49.f);
                    const float lv = sc[t][r] + cv;
                    if (!SPLIT) {
                        out_cov[(size_t)bm * (P_ * P_) + p * 49 + qv] = cv;
                        out_l  [(size_t)bm * (P_ * P_) + p * 49 + qv] = lv;
                    }
                    *(__hip_bfloat16*)(smem + GB_OFF + p * 128 + ((2 * qv) ^ srowswz(p))) =
                        __float2bfloat16(lv);   // Lb; cols 49..63 keep zeros
                }
            }
        }
    }
    __syncthreads();

    // ---- Phase 6: Ec^T = A^T . L^T (D[c][p]); wave wid -> c in [64wid, +64) ----
    {
        f32x4 acc[4][4];   // [ct][pt]
        #pragma unroll
        for (int i = 0; i < 4; ++i)
            #pragma unroll
            for (int j2 = 0; j2 < 4; ++j2) acc[i][j2] = f32x4{0, 0, 0, 0};

        #pragma unroll
        for (int kc = 0; kc < 2; ++kc) {
            const int cb = 64 * kc + 16 * lh;
            short8 bf[4];
            #pragma unroll
            for (int pt = 0; pt < 4; ++pt) {
                const int brow = 16 * pt + l15;
                bf[pt] = *(const short8*)(smem + GB_OFF + brow * 128 + (cb ^ srowswz(brow)));
            }
            #pragma unroll
            for (int ct = 0; ct < 4; ++ct) {
                const int c = 64 * wid + 16 * ct + l15;
                short8 af;
                #pragma unroll
                for (int j = 0; j < 8; ++j) {
                    const int q2 = 32 * kc + 8 * lh + j;
                    short v = *(const short*)(smem + SA_OFF + q2 * 512 + ((2 * c) ^ srowswz(q2)));
                    if (kc == 1) v = (q2 <= 48) ? v : (short)0;  // sA rows 49..63 unwritten
                    af[j] = v;
                }
                #pragma unroll
                for (int pt = 0; pt < 4; ++pt)
                    acc[ct][pt] = __builtin_amdgcn_mfma_f32_16x16x32_bf16(af, bf[pt], acc[ct][pt], 0, 0, 0);
            }
        }

        if (SPLIT) {
            // Patch-major bf16 Ec staging (56-slot rows).
            __hip_bfloat16* wec = ws_ec + (size_t)bm * WS_PATCH;
            #pragma unroll
            for (int pt = 0; pt < 4; ++pt) {
                const int p = 16 * pt + l15;
                if (p >= (int)WS_ROW) continue;   // pt==3: only l15<8
                #pragma unroll
                for (int ct = 0; ct < 4; ++ct) {
                    #pragma unroll
                    for (int r = 0; r < 4; ++r) {
                        const int c = 64 * wid + 16 * ct + 4 * lh + r;
                        wec[(size_t)c * WS_ROW + p] = __float2bfloat16(acc[ct][pt][r]);
                    }
                }
            }
            // Deferred Sc/cov/L stores (coalesced, after last barrier; values
            // bf16-rounded via Scb/Lb: rel err ~0.4% << tolerance).
            float* sc_g  = out_sc  + (size_t)bm * (P_ * P_);
            float* cov_g = out_cov + (size_t)bm * (P_ * P_);
            float* l_g   = out_l   + (size_t)bm * (P_ * P_);
            for (int e = tid; e < P_ * P_; e += 256) {
                const int p = e / 49, q = e - 49 * p;
                const float scv = __bfloat162float(
                    *(const __hip_bfloat16*)(smem + SCB_OFF + p * 128 + ((2 * q) ^ srowswz(p))));
                const float lvv = __bfloat162float(
                    *(const __hip_bfloat16*)(smem + GB_OFF + p * 128 + ((2 * q) ^ srowswz(p))));
                sc_g[e]  = scv;
                l_g[e]   = lvv;
                cov_g[e] = lvv - scv;
            }
        } else {
            #pragma unroll
            for (int pt = 0; pt < 4; ++pt) {
                const int p = 16 * pt + l15;
                if (p > 48) continue;
                const int i = p / 7, j = p - 7 * (p / 7);
                const size_t base = xpatch + (size_t)i * W_ + j;
                #pragma unroll
                for (int ct = 0; ct < 4; ++ct) {
                    #pragma unroll
                    for (int r = 0; r < 4; ++r) {
                        const int c = 64 * wid + 16 * ct + 4 * lh + r;
                        const size_t g = base + (size_t)c * HW_;
                        const float ec = acc[ct][pt][r];
                        const float xv = __bfloat162float(
                            *(const __hip_bfloat16*)(smem + SA_OFF + p * 512 + ((2 * c) ^ srowswz(p))));
                        out_ec [g] = ec;
                        out_img[g] = xv * fmaf(beta, ec, xv);
                    }
                }
            }
        }
    }
}

// Fold: one block per (b, c-quad, mh) strip: stage 4 channels x 32 patches
// from ws (448B-contiguous rows), read x coalesced fp32, write out_img /
// out_ec as full-line float4 stores.
__global__ __launch_bounds__(256)
void fold_kernel(const __hip_bfloat16* __restrict__ ws_ec,
                 const float* __restrict__ x, const float* __restrict__ betap,
                 float* __restrict__ out_img, float* __restrict__ out_ec)
{
    __shared__ __hip_bfloat16 lec[4][32][56];   // 14,336 B

    const int bid = blockIdx.x;
    const int mh  = bid & 31;
    const int bcg = bid >> 5;          // b*64 + cgroup
    const int b   = bcg >> 6;
    const int c0  = (bcg & 63) << 2;
    const int t   = threadIdx.x;
    const float beta = betap[0];

    // Stage: 4c x 32 patches x 7 short8 segments = 896 16B loads.
    for (int s = t; s < 896; s += 256) {
        const int cc  = s / 224;
        const int rem = s - cc * 224;
        const int k   = rem / 7;
        const int o   = (rem - k * 7) * 8;
        const size_t base = (((size_t)(b << 10) + (mh << 5) + k) * C_ + (c0 + cc)) * WS_ROW + o;
        *(short8*)&lec[cc][k][o] = *(const short8*)&ws_ec[base];
    }
    __syncthreads();

    // Emit: 4 channels x 7 rows x 56 float4s = 1568 iterations.
    for (int idx = t; idx < 1568; idx += 256) {
        const int cc = idx / 392;
        const int r2 = idx - cc * 392;
        const int i  = r2 / 56;
        const int w0 = (r2 - i * 56) * 4;
        const size_t g = (((size_t)(b * C_ + c0 + cc)) * H_ + (size_t)mh * 7 + i) * W_ + w0;
        const float4 xv = *(const float4*)&x[g];
        float4 vo, ve;
        #pragma unroll
        for (int e = 0; e < 4; ++e) {
            const int w  = w0 + e;
            const int mw = w / 7;
            const int p  = i * 7 + (w - mw * 7);
            const float ec = __bfloat162float(lec[cc][mw][p]);
            const float xe = ((const float*)&xv)[e];
            ((float*)&ve)[e] = ec;
            ((float*)&vo)[e] = xe * fmaf(beta, ec, xe);
        }
        *(float4*)&out_ec [g] = ve;
        *(float4*)&out_img[g] = vo;
    }
}

extern "C" void kernel_launch(void* const* d_in, const int* in_sizes, int n_in,
                              void* d_out, int out_size, void* d_ws, size_t ws_size,
                              hipStream_t stream) {
    const float* x    = (const float*)d_in[0];
    const float* beta = (const float*)d_in[1];
    float* out = (float*)d_out;

    if (ws_size >= WS_NEED) {
        __hip_bfloat16* ws_ec = (__hip_bfloat16*)d_ws;
        psa_kernel<true><<<dim3(4 * M_), dim3(256), 0, stream>>>(
            x, beta, out, out + OFF_SC, out + OFF_COV, out + OFF_L, out + OFF_EC,
            ws_ec);
        fold_kernel<<<dim3(8192), dim3(256), 0, stream>>>(
            ws_ec, x, beta, out, out + OFF_EC);
    } else {
        psa_kernel<false><<<dim3(4 * M_), dim3(256), 0, stream>>>(
            x, beta, out, out + OFF_SC, out + OFF_COV, out + OFF_L, out + OFF_EC,
            nullptr);
    }
}

// Round 11
// 285.514 us; speedup vs baseline: 1.0133x; 1.0133x over previous
//
#include <hip/hip_runtime.h>
#include <hip/hip_bf16.h>
#include <cstdint>
#include <cstddef>

constexpr int C_  = 256;
constexpr int H_  = 224;
constexpr int W_  = 224;
constexpr int P_  = 49;
constexpr int M_  = 1024;
constexpr int HW_ = H_ * W_;

constexpr size_t IMG_ELEMS = (size_t)4 * C_ * H_ * W_;
constexpr size_t SCO_ELEMS = (size_t)4 * M_ * P_ * P_;
constexpr size_t OFF_SC  = IMG_ELEMS;
constexpr size_t OFF_COV = OFF_SC  + SCO_ELEMS;
constexpr size_t OFF_L   = OFF_COV + SCO_ELEMS;
constexpr size_t OFF_EC  = OFF_L   + SCO_ELEMS;

typedef __attribute__((ext_vector_type(8))) short short8;
typedef __attribute__((ext_vector_type(4))) float f32x4;

// Workspace: patch-major bf16 Ec staging, 56 p-slots per (bm,c) row (112B).
constexpr size_t WS_ROW   = 56;
constexpr size_t WS_PATCH = (size_t)C_ * WS_ROW;              // 14336 elems
constexpr size_t WS_NEED  = (size_t)4096 * WS_PATCH * 2;      // 117,440,512 B

// LDS byte map (compute kernel, 40,960 B -> 4 blocks/CU):
//   sA  : [0, 32768)        64 rows x 512B bf16, row-XOR-swizzled
//                           (rows 49..63 zeroed by idle lanes in P0)
//   Gb  : [25088+7680=32768? no — see below]
// Actually: sA uses rows 0..63 now (rows 49..63 zeroed): 64*512 = 32768.
//   Gb  : [32768, 39040)    49 rows x 128B bf16 (G - u); Lb overlays after cov
//   Scb : [39040, 45312)    49 rows x 128B bf16 Sc
//   u   : [45312, 45568)    64 f32
// Total 45,568 B -> 3 blocks/CU?? No: keep rows 49..63 OVERLAPPING the old
// layout is unsafe. Resolution: zero only the 128B quarter each wave owns in
// rows 49..63 is NOT possible within 37,888B. We instead keep the original
// 49-row sA and have idle lanes zero a dedicated 15-row region is what the
// larger map above provides. Chosen: extended sA (64 rows) at +7,680 B.
// Final map (45,568 B <= 53,333 -> still 3 blocks/CU at worst; measured R8:
// 3 vs 4 blocks/CU made no difference, so this is safe):
constexpr int SA_OFF  = 0;        // 64 rows x 512B = 32768
constexpr int GB_OFF  = 32768;    // 49 x 128B = 6272
constexpr int SCB_OFF = 39040;    // 49 x 128B = 6272
constexpr int U_OFF   = 45312;    // 64 f32
constexpr int SMEM_BYTES = 45568;

// G lives in MFMA accumulators; softmax in-register; fp32 Sc carried in regs
// to the L epilogue; T2 = rowmean of the cov accumulator (exact identity).
// Sc/cov/L global stores deferred to after the last barrier (bf16-rounded
// via Scb/Lb; rel err ~0.4% << tolerance). sA rows 49..63 are explicit
// zeros, so ALL out-of-range fragment reads are exact zeros (no masking
// needed anywhere; garbage only in discarded D rows/cols).

__device__ __forceinline__ int srowswz(int r) { return ((r ^ (r >> 3)) & 7) << 4; }

__device__ __forceinline__ short f2bf_s(float v) {
    __hip_bfloat16 b = __float2bfloat16(v);
    return *reinterpret_cast<short*>(&b);
}

template<bool SPLIT>
__global__ __launch_bounds__(256, 3)
void psa_kernel(const float* __restrict__ x, const float* __restrict__ betap,
                float* __restrict__ out_img, float* __restrict__ out_sc,
                float* __restrict__ out_cov, float* __restrict__ out_l,
                float* __restrict__ out_ec,
                __hip_bfloat16* __restrict__ ws_ec)
{
    __shared__ __align__(16) unsigned char smem[SMEM_BYTES];
    float* uArr = (float*)(smem + U_OFF);

    const int tid = threadIdx.x;
    const int bid = blockIdx.x;
    const int bm  = ((bid & 7) << 9) | (bid >> 3);   // XCD-bijective swizzle
    const int b   = bm >> 10;
    const int m   = bm & (M_ - 1);
    const int mh  = m >> 5;
    const int mw  = m & 31;
    const float beta = betap[0];
    const size_t xpatch = (((size_t)b * C_ * H_) + (size_t)mh * 7) * W_ + (size_t)mw * 7;

    const int wid = tid >> 6, lane = tid & 63, l15 = lane & 15, lh = lane >> 4;

    // ---- Phase 0: stage x -> sA. lane = token p; wave wid covers channels
    // [64wid, 64wid+64). 8 channels packed per ds_write_b128 (swizzle only
    // touches byte-bits 4-6, so aligned 16B groups stay contiguous).
    // Lanes 49..63 zero their rows (hardens overflow reads to exact 0). ----
    {
        const int p = lane;
        const int i = p / 7, j = p - 7 * (p / 7);
        const float* xp = x + xpatch + (size_t)i * W_ + j + (size_t)(64 * wid) * HW_;
        const int swzp = srowswz(p);
        unsigned char* sbase = smem + SA_OFF + p * 512 + 128 * wid;
        #pragma unroll
        for (int g = 0; g < 8; ++g) {
            short8 pk;
            if (p < P_) {
                #pragma unroll
                for (int k = 0; k < 8; ++k)
                    pk[k] = f2bf_s(xp[(size_t)(8 * g + k) * HW_]);
            } else {
                pk = short8{0, 0, 0, 0, 0, 0, 0, 0};
            }
            *(short8*)(sbase + ((16 * g) ^ swzp)) = pk;
        }
    }
    __syncthreads();

    // ---- Phase 1: G = A A^T (MFMA, K=256); G stays in registers ----
    f32x4 gacc[4] = {f32x4{0,0,0,0}, f32x4{0,0,0,0}, f32x4{0,0,0,0}, f32x4{0,0,0,0}};
    {
        const int arow = 16 * wid + l15;
        #pragma unroll
        for (int kc = 0; kc < 8; ++kc) {
            const int cb = 64 * kc + 16 * lh;
            const short8 af = *(const short8*)(smem + SA_OFF + arow * 512 + (cb ^ srowswz(arow)));
            #pragma unroll
            for (int t = 0; t < 4; ++t) {
                const int brow = 16 * t + l15;
                const short8 bf = *(const short8*)(smem + SA_OFF + brow * 512 + (cb ^ srowswz(brow)));
                gacc[t] = __builtin_amdgcn_mfma_f32_16x16x32_bf16(af, bf, gacc[t], 0, 0, 0);
            }
        }
    }

    // ---- Phase 2: in-register row stats (lane holds G[p][q], p=16wid+4lh+r,
    // q=16t+l15); u = rowmean (G symmetric) ----
    float mx[4];
    {
        #pragma unroll
        for (int r = 0; r < 4; ++r) {
            const int p = 16 * wid + 4 * lh + r;
            float m_ = fmaxf(fmaxf(gacc[0][r], gacc[1][r]), gacc[2][r]);
            m_ = fmaxf(m_, (l15 == 0) ? gacc[3][r] : -3.4e38f);
            float s_ = gacc[0][r] + gacc[1][r] + gacc[2][r] + ((l15 == 0) ? gacc[3][r] : 0.f);
            #pragma unroll
            for (int d = 1; d < 16; d <<= 1) {
                m_ = fmaxf(m_, __shfl_xor(m_, d));
                s_ += __shfl_xor(s_, d);
            }
            mx[r] = m_;
            if (l15 == 0 && p <= 48) uArr[p] = s_ * (1.f / 49.f);
        }
    }
    __syncthreads();

    // ---- Phase 3: Gb = bf16(G-u); in-reg exp/rowsum/scale; Scb ----
    float sc[4][4];   // fp32 Sc carried to the L epilogue
    {
        #pragma unroll
        for (int r = 0; r < 4; ++r) {
            const int p = 16 * wid + 4 * lh + r;
            if (p <= 48) {
                #pragma unroll
                for (int t = 0; t < 4; ++t) {
                    const int qv = 16 * t + l15;
                    const float gv = (qv <= 48) ? (gacc[t][r] - uArr[qv]) : 0.f;
                    *(__hip_bfloat16*)(smem + GB_OFF + p * 128 + ((2 * qv) ^ srowswz(p))) =
                        __float2bfloat16(gv);
                }
            }
            float e[4];
            #pragma unroll
            for (int t = 0; t < 4; ++t) {
                const int qv = 16 * t + l15;
                e[t] = (qv <= 48) ? __expf(gacc[t][r] - mx[r]) : 0.f;
            }
            float s_ = e[0] + e[1] + e[2] + e[3];
            #pragma unroll
            for (int d = 1; d < 16; d <<= 1) s_ += __shfl_xor(s_, d);
            const float rinv = 1.f / s_;
            #pragma unroll
            for (int t = 0; t < 4; ++t) sc[t][r] = e[t] * rinv;
            if (p <= 48) {
                #pragma unroll
                for (int t = 0; t < 4; ++t) {
                    const int qv = 16 * t + l15;
                    *(__hip_bfloat16*)(smem + SCB_OFF + p * 128 + ((2 * qv) ^ srowswz(p))) =
                        __float2bfloat16(sc[t][r]);        // qv>48 stores 0
                    if (!SPLIT && qv <= 48)
                        out_sc[(size_t)bm * (P_ * P_) + p * 49 + qv] = sc[t][r];
                }
            }
        }
    }
    __syncthreads();

    // ---- Phase 4: cov MFMA: cacc = Gb . Scb^T (K=64); T2 = rowmean in-reg ----
    f32x4 cacc[4] = {f32x4{0,0,0,0}, f32x4{0,0,0,0}, f32x4{0,0,0,0}, f32x4{0,0,0,0}};
    {
        const int arow = 16 * wid + l15;
        #pragma unroll
        for (int kc = 0; kc < 2; ++kc) {
            const int cb = 64 * kc + 16 * lh;
            const short8 af = *(const short8*)(smem + GB_OFF + arow * 128 + (cb ^ srowswz(arow)));
            #pragma unroll
            for (int t = 0; t < 4; ++t) {
                const int brow = 16 * t + l15;
                const short8 bf = *(const short8*)(smem + SCB_OFF + brow * 128 + (cb ^ srowswz(brow)));
                cacc[t] = __builtin_amdgcn_mfma_f32_16x16x32_bf16(af, bf, cacc[t], 0, 0, 0);
            }
        }
    }
    float t2[4];
    {
        #pragma unroll
        for (int r = 0; r < 4; ++r) {
            float s_ = cacc[0][r] + cacc[1][r] + cacc[2][r] + ((l15 == 0) ? cacc[3][r] : 0.f);
            #pragma unroll
            for (int d = 1; d < 16; d <<= 1) s_ += __shfl_xor(s_, d);
            t2[r] = s_ * (1.f / 49.f);
        }
    }
    __syncthreads();   // cov reads done before Lb overlays Gb

    // ---- Phase 5: cv = (cacc - T2)/49; L = Sc + cv; Lb LDS write ----
    {
        #pragma unroll
        for (int t = 0; t < 4; ++t) {
            const int qv = 16 * t + l15;
            #pragma unroll
            for (int r = 0; r < 4; ++r) {
                const int p = 16 * wid + 4 * lh + r;
                if (p <= 48 && qv <= 48) {
                    const float cv = (cacc[t][r] - t2[r]) * (1.f / 49.f);
                    const float lv = sc[t][r] + cv;
                    if (!SPLIT) {
                        out_cov[(size_t)bm * (P_ * P_) + p * 49 + qv] = cv;
                        out_l  [(size_t)bm * (P_ * P_) + p * 49 + qv] = lv;
                    }
                    *(__hip_bfloat16*)(smem + GB_OFF + p * 128 + ((2 * qv) ^ srowswz(p))) =
                        __float2bfloat16(lv);   // Lb; cols 49..63 keep zeros
                }
            }
        }
    }
    __syncthreads();

    // ---- Phase 6: Ec^T = A^T . L^T (D[c][p]); wave wid -> c in [64wid, +64).
    // sA rows 49..63 are zeros, so no masking needed on the column reads. ----
    {
        f32x4 acc[4][4];   // [ct][pt]
        #pragma unroll
        for (int i = 0; i < 4; ++i)
            #pragma unroll
            for (int j2 = 0; j2 < 4; ++j2) acc[i][j2] = f32x4{0, 0, 0, 0};

        #pragma unroll
        for (int kc = 0; kc < 2; ++kc) {
            const int cb = 64 * kc + 16 * lh;
            short8 bf[4];
            #pragma unroll
            for (int pt = 0; pt < 4; ++pt) {
                const int brow = 16 * pt + l15;
                bf[pt] = *(const short8*)(smem + GB_OFF + brow * 128 + (cb ^ srowswz(brow)));
            }
            #pragma unroll
            for (int ct = 0; ct < 4; ++ct) {
                const int c = 64 * wid + 16 * ct + l15;
                short8 af;
                #pragma unroll
                for (int j = 0; j < 8; ++j) {
                    const int q2 = 32 * kc + 8 * lh + j;
                    af[j] = *(const short*)(smem + SA_OFF + q2 * 512 + ((2 * c) ^ srowswz(q2)));
                }
                #pragma unroll
                for (int pt = 0; pt < 4; ++pt)
                    acc[ct][pt] = __builtin_amdgcn_mfma_f32_16x16x32_bf16(af, bf[pt], acc[ct][pt], 0, 0, 0);
            }
        }

        if (SPLIT) {
            // Patch-major bf16 Ec staging (56-slot rows).
            __hip_bfloat16* wec = ws_ec + (size_t)bm * WS_PATCH;
            #pragma unroll
            for (int pt = 0; pt < 4; ++pt) {
                const int p = 16 * pt + l15;
                if (p >= (int)WS_ROW) continue;   // pt==3: only l15<8
                #pragma unroll
                for (int ct = 0; ct < 4; ++ct) {
                    #pragma unroll
                    for (int r = 0; r < 4; ++r) {
                        const int c = 64 * wid + 16 * ct + 4 * lh + r;
                        wec[(size_t)c * WS_ROW + p] = __float2bfloat16(acc[ct][pt][r]);
                    }
                }
            }
            // Deferred Sc/cov/L stores (coalesced, after last barrier; values
            // bf16-rounded via Scb/Lb: rel err ~0.4% << tolerance).
            float* sc_g  = out_sc  + (size_t)bm * (P_ * P_);
            float* cov_g = out_cov + (size_t)bm * (P_ * P_);
            float* l_g   = out_l   + (size_t)bm * (P_ * P_);
            for (int e = tid; e < P_ * P_; e += 256) {
                const int p = e / 49, q = e - 49 * p;
                const float scv = __bfloat162float(
                    *(const __hip_bfloat16*)(smem + SCB_OFF + p * 128 + ((2 * q) ^ srowswz(p))));
                const float lvv = __bfloat162float(
                    *(const __hip_bfloat16*)(smem + GB_OFF + p * 128 + ((2 * q) ^ srowswz(p))));
                sc_g[e]  = scv;
                l_g[e]   = lvv;
                cov_g[e] = lvv - scv;
            }
        } else {
            #pragma unroll
            for (int pt = 0; pt < 4; ++pt) {
                const int p = 16 * pt + l15;
                if (p > 48) continue;
                const int i = p / 7, j = p - 7 * (p / 7);
                const size_t base = xpatch + (size_t)i * W_ + j;
                #pragma unroll
                for (int ct = 0; ct < 4; ++ct) {
                    #pragma unroll
                    for (int r = 0; r < 4; ++r) {
                        const int c = 64 * wid + 16 * ct + 4 * lh + r;
                        const size_t g = base + (size_t)c * HW_;
                        const float ec = acc[ct][pt][r];
                        const float xv = __bfloat162float(
                            *(const __hip_bfloat16*)(smem + SA_OFF + p * 512 + ((2 * c) ^ srowswz(p))));
                        out_ec [g] = ec;
                        out_img[g] = xv * fmaf(beta, ec, xv);
                    }
                }
            }
        }
    }
}

// Fold: one block per (b, c-quad, mh) strip: stage 4 channels x 32 patches
// from ws (448B-contiguous rows), read x coalesced fp32, write out_img /
// out_ec as full-line float4 stores.
__global__ __launch_bounds__(256)
void fold_kernel(const __hip_bfloat16* __restrict__ ws_ec,
                 const float* __restrict__ x, const float* __restrict__ betap,
                 float* __restrict__ out_img, float* __restrict__ out_ec)
{
    __shared__ __hip_bfloat16 lec[4][32][56];   // 14,336 B

    const int bid = blockIdx.x;
    const int mh  = bid & 31;
    const int bcg = bid >> 5;          // b*64 + cgroup
    const int b   = bcg >> 6;
    const int c0  = (bcg & 63) << 2;
    const int t   = threadIdx.x;
    const float beta = betap[0];

    // Stage: 4c x 32 patches x 7 short8 segments = 896 16B loads.
    for (int s = t; s < 896; s += 256) {
        const int cc  = s / 224;
        const int rem = s - cc * 224;
        const int k   = rem / 7;
        const int o   = (rem - k * 7) * 8;
        const size_t base = (((size_t)(b << 10) + (mh << 5) + k) * C_ + (c0 + cc)) * WS_ROW + o;
        *(short8*)&lec[cc][k][o] = *(const short8*)&ws_ec[base];
    }
    __syncthreads();

    // Emit: 4 channels x 7 rows x 56 float4s = 1568 iterations.
    for (int idx = t; idx < 1568; idx += 256) {
        const int cc = idx / 392;
        const int r2 = idx - cc * 392;
        const int i  = r2 / 56;
        const int w0 = (r2 - i * 56) * 4;
        const size_t g = (((size_t)(b * C_ + c0 + cc)) * H_ + (size_t)mh * 7 + i) * W_ + w0;
        const float4 xv = *(const float4*)&x[g];
        float4 vo, ve;
        #pragma unroll
        for (int e = 0; e < 4; ++e) {
            const int w  = w0 + e;
            const int mw = w / 7;
            const int p  = i * 7 + (w - mw * 7);
            const float ec = __bfloat162float(lec[cc][mw][p]);
            const float xe = ((const float*)&xv)[e];
            ((float*)&ve)[e] = ec;
            ((float*)&vo)[e] = xe * fmaf(beta, ec, xe);
        }
        *(float4*)&out_ec [g] = ve;
        *(float4*)&out_img[g] = vo;
    }
}

extern "C" void kernel_launch(void* const* d_in, const int* in_sizes, int n_in,
                              void* d_out, int out_size, void* d_ws, size_t ws_size,
                              hipStream_t stream) {
    const float* x    = (const float*)d_in[0];
    const float* beta = (const float*)d_in[1];
    float* out = (float*)d_out;

    if (ws_size >= WS_NEED) {
        __hip_bfloat16* ws_ec = (__hip_bfloat16*)d_ws;
        psa_kernel<true><<<dim3(4 * M_), dim3(256), 0, stream>>>(
            x, beta, out, out + OFF_SC, out + OFF_COV, out + OFF_L, out + OFF_EC,
            ws_ec);
        fold_kernel<<<dim3(8192), dim3(256), 0, stream>>>(
            ws_ec, x, beta, out, out + OFF_EC);
    } else {
        psa_kernel<false><<<dim3(4 * M_), dim3(256), 0, stream>>>(
            x, beta, out, out + OFF_SC, out + OFF_COV, out + OFF_L, out + OFF_EC,
            nullptr);
    }
}